// Round 3
// baseline (580.694 us; speedup 1.0000x reference)
//
#include <hip/hip_runtime.h>

#define R_BINS 50
#define NFEAT 7
#define HSZ (R_BINS * NFEAT)    // 350 floats used per copy
#define CSTRIDE 351             // odd stride: copy c starts at bank -c mod 32
#define NCOPY 32                // lane-indexed sub-copies

__device__ __forceinline__ void lds_add(float* p, float v) {
    // relaxed, workgroup-scope float add on LDS: the legal path to ds_add_f32
    __hip_atomic_fetch_add(p, v, __ATOMIC_RELAXED, __HIP_MEMORY_SCOPE_WORKGROUP);
}

__device__ __forceinline__ void glob_add(float* p, float v) {
    __hip_atomic_fetch_add(p, v, __ATOMIC_RELAXED, __HIP_MEMORY_SCOPE_AGENT);
}

__global__ __launch_bounds__(256) void disk_hist_kernel(
    const float* __restrict__ pos,
    const float* __restrict__ vel,
    const float* __restrict__ mass,
    float* __restrict__ ghist,
    int n)
{
    __shared__ float sh[NCOPY * CSTRIDE];   // 44.9 KB -> 3 blocks/CU

    for (int i = threadIdx.x; i < NCOPY * CSTRIDE; i += blockDim.x)
        sh[i] = 0.0f;
    __syncthreads();

    float* h = sh + (threadIdx.x & (NCOPY - 1)) * CSTRIDE;

    const int tid    = blockIdx.x * blockDim.x + threadIdx.x;
    const int stride = gridDim.x * blockDim.x;
    const int nquads = n >> 2;

    const float4* pos4  = (const float4*)pos;
    const float4* vel4  = (const float4*)vel;
    const float4* mass4 = (const float4*)mass;

    for (int q = tid; q < nquads; q += stride) {
        float4 p0 = pos4[3*q + 0];
        float4 p1 = pos4[3*q + 1];
        float4 p2 = pos4[3*q + 2];
        float4 v0 = vel4[3*q + 0];
        float4 v1 = vel4[3*q + 1];
        float4 v2 = vel4[3*q + 2];
        float4 m  = mass4[q];

        float px[4] = {p0.x, p0.w, p1.z, p2.y};
        float py[4] = {p0.y, p1.x, p1.w, p2.z};
        float vx[4] = {v0.x, v0.w, v1.z, v2.y};
        float vy[4] = {v0.y, v1.x, v1.w, v2.z};
        float vz[4] = {v0.z, v1.y, v2.x, v2.w};
        float mm[4] = {m.x,  m.y,  m.z,  m.w};

        #pragma unroll
        for (int k = 0; k < 4; ++k) {
            float x = px[k], y = py[k];
            float r = sqrtf(x * x + y * y);
            int bin = (int)floorf(r / 0.2f);
            if (bin < 0 || bin >= R_BINS) continue;
            float invr = 1.0f / r;
            float vr = (x * vx[k] + y * vy[k]) * invr;
            float vp = (y * vx[k] - x * vy[k]) * invr;
            float w  = mm[k];
            float* b = h + bin * NFEAT;
            lds_add(b + 0, w);
            lds_add(b + 1, w * vr);
            lds_add(b + 2, w * vr * vr);
            lds_add(b + 3, w * vp);
            lds_add(b + 4, w * vp * vp);
            lds_add(b + 5, w * vz[k]);
            lds_add(b + 6, w * vz[k] * vz[k]);
        }
    }

    // scalar tail
    for (int p = (nquads << 2) + tid; p < n; p += stride) {
        float x = pos[3*p], y = pos[3*p + 1];
        float r = sqrtf(x * x + y * y);
        int bin = (int)floorf(r / 0.2f);
        if (bin < 0 || bin >= R_BINS) continue;
        float invr = 1.0f / r;
        float vxs = vel[3*p], vys = vel[3*p + 1], vzs = vel[3*p + 2];
        float vr = (x * vxs + y * vys) * invr;
        float vp = (y * vxs - x * vys) * invr;
        float w  = mass[p];
        float* b = h + bin * NFEAT;
        lds_add(b + 0, w);
        lds_add(b + 1, w * vr);
        lds_add(b + 2, w * vr * vr);
        lds_add(b + 3, w * vp);
        lds_add(b + 4, w * vp * vp);
        lds_add(b + 5, w * vzs);
        lds_add(b + 6, w * vzs * vzs);
    }

    __syncthreads();

    // merge the 32 copies; one global atomic per cell per block
    for (int i = threadIdx.x; i < HSZ; i += blockDim.x) {
        float s = 0.0f;
        #pragma unroll
        for (int c = 0; c < NCOPY; ++c)
            s += sh[c * CSTRIDE + i];
        glob_add(ghist + i, s);
    }
}

__global__ void disk_finalize_kernel(const float* __restrict__ gh,
                                     float* __restrict__ out)
{
    int b = threadIdx.x;
    if (b >= R_BINS) return;
    const float* s = gh + b * NFEAT;
    float inv  = 1.0f / s[0];
    float vr_m = s[1] * inv, vr2 = s[2] * inv;
    float vp_m = s[3] * inv, vp2 = s[4] * inv;
    float vz_m = s[5] * inv, vz2 = s[6] * inv;
    out[0 * R_BINS + b] = vp_m;
    out[1 * R_BINS + b] = sqrtf(vp2 - vp_m * vp_m);
    out[2 * R_BINS + b] = vr_m;
    out[3 * R_BINS + b] = sqrtf(vr2 - vr_m * vr_m);
    out[4 * R_BINS + b] = vz_m;
    out[5 * R_BINS + b] = sqrtf(vz2 - vz_m * vz_m);
}

extern "C" void kernel_launch(void* const* d_in, const int* in_sizes, int n_in,
                              void* d_out, int out_size, void* d_ws, size_t ws_size,
                              hipStream_t stream)
{
    const float* pos  = (const float*)d_in[0];
    const float* vel  = (const float*)d_in[1];
    const float* mass = (const float*)d_in[2];
    float* out   = (float*)d_out;
    float* ghist = (float*)d_ws;
    int n = in_sizes[2];   // masses: one per particle

    hipMemsetAsync(ghist, 0, HSZ * sizeof(float), stream);

    disk_hist_kernel<<<768, 256, 0, stream>>>(pos, vel, mass, ghist, n);
    disk_finalize_kernel<<<1, 64, 0, stream>>>(ghist, out);
}

// Round 4
// 580.016 us; speedup vs baseline: 1.0012x; 1.0012x over previous
//
#include <hip/hip_runtime.h>

#define R_BINS 50
#define NFEAT 7
#define HSZ (R_BINS * NFEAT)    // 350 floats used per copy
#define CSTRIDE 351             // odd stride: copies start in distinct banks
#define NCOPY 32                // lane-indexed sub-copies

// Native fp32 atomics: unsafeAtomicAdd sets amdgpu-unsafe-fp-atomics on the
// function, lowering to ds_add_f32 (LDS) / global_atomic_add_f32 (global)
// instead of the default IEEE-safe CAS loop. Return value ignored -> no-rtn.
__device__ __forceinline__ void lds_add(float* p, float v) {
    unsafeAtomicAdd(p, v);
}

__device__ __forceinline__ void glob_add(float* p, float v) {
    unsafeAtomicAdd(p, v);
}

__global__ __launch_bounds__(256) void disk_hist_kernel(
    const float* __restrict__ pos,
    const float* __restrict__ vel,
    const float* __restrict__ mass,
    float* __restrict__ ghist,
    int n)
{
    __shared__ float sh[NCOPY * CSTRIDE];   // 44.9 KB -> 3 blocks/CU

    for (int i = threadIdx.x; i < NCOPY * CSTRIDE; i += blockDim.x)
        sh[i] = 0.0f;
    __syncthreads();

    float* h = sh + (threadIdx.x & (NCOPY - 1)) * CSTRIDE;

    const int tid    = blockIdx.x * blockDim.x + threadIdx.x;
    const int stride = gridDim.x * blockDim.x;
    const int nquads = n >> 2;

    const float4* pos4  = (const float4*)pos;
    const float4* vel4  = (const float4*)vel;
    const float4* mass4 = (const float4*)mass;

    for (int q = tid; q < nquads; q += stride) {
        float4 p0 = pos4[3*q + 0];
        float4 p1 = pos4[3*q + 1];
        float4 p2 = pos4[3*q + 2];
        float4 v0 = vel4[3*q + 0];
        float4 v1 = vel4[3*q + 1];
        float4 v2 = vel4[3*q + 2];
        float4 m  = mass4[q];

        float px[4] = {p0.x, p0.w, p1.z, p2.y};
        float py[4] = {p0.y, p1.x, p1.w, p2.z};
        float vx[4] = {v0.x, v0.w, v1.z, v2.y};
        float vy[4] = {v0.y, v1.x, v1.w, v2.z};
        float vz[4] = {v0.z, v1.y, v2.x, v2.w};
        float mm[4] = {m.x,  m.y,  m.z,  m.w};

        #pragma unroll
        for (int k = 0; k < 4; ++k) {
            float x = px[k], y = py[k];
            float r = sqrtf(x * x + y * y);
            int bin = (int)floorf(r / 0.2f);
            if (bin < 0 || bin >= R_BINS) continue;
            float invr = 1.0f / r;
            float vr = (x * vx[k] + y * vy[k]) * invr;
            float vp = (y * vx[k] - x * vy[k]) * invr;
            float w  = mm[k];
            float* b = h + bin * NFEAT;
            lds_add(b + 0, w);
            lds_add(b + 1, w * vr);
            lds_add(b + 2, w * vr * vr);
            lds_add(b + 3, w * vp);
            lds_add(b + 4, w * vp * vp);
            lds_add(b + 5, w * vz[k]);
            lds_add(b + 6, w * vz[k] * vz[k]);
        }
    }

    // scalar tail
    for (int p = (nquads << 2) + tid; p < n; p += stride) {
        float x = pos[3*p], y = pos[3*p + 1];
        float r = sqrtf(x * x + y * y);
        int bin = (int)floorf(r / 0.2f);
        if (bin < 0 || bin >= R_BINS) continue;
        float invr = 1.0f / r;
        float vxs = vel[3*p], vys = vel[3*p + 1], vzs = vel[3*p + 2];
        float vr = (x * vxs + y * vys) * invr;
        float vp = (y * vxs - x * vys) * invr;
        float w  = mass[p];
        float* b = h + bin * NFEAT;
        lds_add(b + 0, w);
        lds_add(b + 1, w * vr);
        lds_add(b + 2, w * vr * vr);
        lds_add(b + 3, w * vp);
        lds_add(b + 4, w * vp * vp);
        lds_add(b + 5, w * vzs);
        lds_add(b + 6, w * vzs * vzs);
    }

    __syncthreads();

    // merge the 32 copies; one global atomic per cell per block
    for (int i = threadIdx.x; i < HSZ; i += blockDim.x) {
        float s = 0.0f;
        #pragma unroll
        for (int c = 0; c < NCOPY; ++c)
            s += sh[c * CSTRIDE + i];
        glob_add(ghist + i, s);
    }
}

__global__ void disk_finalize_kernel(const float* __restrict__ gh,
                                     float* __restrict__ out)
{
    int b = threadIdx.x;
    if (b >= R_BINS) return;
    const float* s = gh + b * NFEAT;
    float inv  = 1.0f / s[0];
    float vr_m = s[1] * inv, vr2 = s[2] * inv;
    float vp_m = s[3] * inv, vp2 = s[4] * inv;
    float vz_m = s[5] * inv, vz2 = s[6] * inv;
    out[0 * R_BINS + b] = vp_m;
    out[1 * R_BINS + b] = sqrtf(vp2 - vp_m * vp_m);
    out[2 * R_BINS + b] = vr_m;
    out[3 * R_BINS + b] = sqrtf(vr2 - vr_m * vr_m);
    out[4 * R_BINS + b] = vz_m;
    out[5 * R_BINS + b] = sqrtf(vz2 - vz_m * vz_m);
}

extern "C" void kernel_launch(void* const* d_in, const int* in_sizes, int n_in,
                              void* d_out, int out_size, void* d_ws, size_t ws_size,
                              hipStream_t stream)
{
    const float* pos  = (const float*)d_in[0];
    const float* vel  = (const float*)d_in[1];
    const float* mass = (const float*)d_in[2];
    float* out   = (float*)d_out;
    float* ghist = (float*)d_ws;
    int n = in_sizes[2];   // masses: one per particle

    hipMemsetAsync(ghist, 0, HSZ * sizeof(float), stream);

    disk_hist_kernel<<<768, 256, 0, stream>>>(pos, vel, mass, ghist, n);
    disk_finalize_kernel<<<1, 64, 0, stream>>>(ghist, out);
}

// Round 6
// 142.577 us; speedup vs baseline: 4.0729x; 4.0681x over previous
//
#include <hip/hip_runtime.h>

#define R_BINS 50
#define NFEAT 7
#define HSZ (R_BINS * NFEAT)     // 350
#define STRIDE_ST 268            // staging row stride in floats (256 + 12 pad)

typedef __attribute__((ext_vector_type(8))) short short8;  // 8 bf16 (4 VGPRs)
typedef __attribute__((ext_vector_type(4))) float f32x4;

// pack two f32 -> two bf16 (RNE), a in low 16, b in high 16
__device__ __forceinline__ unsigned pk2bf(float a, float b) {
    unsigned ua = __builtin_bit_cast(unsigned, a);
    unsigned ub = __builtin_bit_cast(unsigned, b);
    ua = (ua + 0x7FFFu + ((ua >> 16) & 1u)) >> 16;
    ub = (ub + 0x7FFFu + ((ub >> 16) & 1u)) & 0xFFFF0000u;
    return ua | ub;
}

__global__ __launch_bounds__(256) void disk_hist_kernel(
    const float* __restrict__ pos,
    const float* __restrict__ vel,
    const float* __restrict__ mass,
    float* __restrict__ ghist,
    int n)
{
    __shared__ float st[8][STRIDE_ST];   // rows 0..6: w*feat, row 7: bin as float
    __shared__ float mg[4][HSZ];         // per-wave partial histograms (merge)

    const int tid  = threadIdx.x;
    const int lane = tid & 63;
    const int w    = tid >> 6;     // wave in block
    const int col  = lane & 15;    // B: feature col / A: bin row (within tile)
    const int g    = lane >> 4;    // k-group (8 particles per group)

    f32x4 acc[4] = {{0,0,0,0},{0,0,0,0},{0,0,0,0},{0,0,0,0}};

    const int stride = gridDim.x * blockDim.x;
    const int gtid   = blockIdx.x * blockDim.x + tid;
    const int nquads = n >> 2;
    const int niter  = (nquads + stride - 1) / stride;   // block-uniform

    const float4* pos4  = (const float4*)pos;
    const float4* vel4  = (const float4*)vel;
    const float4* mass4 = (const float4*)mass;

    for (int it = 0; it < niter; ++it) {
        int q = it * stride + gtid;
        bool valid = q < nquads;
        float px[4], py[4], vx[4], vy[4], vzc[4], mm[4];
        if (valid) {
            float4 p0 = pos4[3*q+0], p1 = pos4[3*q+1], p2 = pos4[3*q+2];
            float4 v0 = vel4[3*q+0], v1 = vel4[3*q+1], v2 = vel4[3*q+2];
            float4 m  = mass4[q];
            px[0]=p0.x; px[1]=p0.w; px[2]=p1.z; px[3]=p2.y;
            py[0]=p0.y; py[1]=p1.x; py[2]=p1.w; py[3]=p2.z;
            vx[0]=v0.x; vx[1]=v0.w; vx[2]=v1.z; vx[3]=v2.y;
            vy[0]=v0.y; vy[1]=v1.x; vy[2]=v1.w; vy[3]=v2.z;
            vzc[0]=v0.z; vzc[1]=v1.y; vzc[2]=v2.x; vzc[3]=v2.w;
            mm[0]=m.x;  mm[1]=m.y;  mm[2]=m.z;  mm[3]=m.w;
        } else {
            #pragma unroll
            for (int k2 = 0; k2 < 4; ++k2) {
                px[k2]=py[k2]=vx[k2]=vy[k2]=vzc[k2]=mm[k2]=0.0f;
            }
        }

        #pragma unroll
        for (int k = 0; k < 4; ++k) {
            // ---- compute w-weighted features for this thread's particle ----
            float x = px[k], y = py[k];
            float r = sqrtf(x*x + y*y);
            // GUARD: padded lanes (x=y=0) must stage exact zeros, not 0*inf=NaN
            float invr = (r > 0.0f) ? (1.0f / r) : 0.0f;
            float binf = (valid && r > 0.0f) ? floorf(r * 5.0f) : -1.0f; // DR=0.2
            float vr = (x*vx[k] + y*vy[k]) * invr;
            float vp = (y*vx[k] - x*vy[k]) * invr;
            float wg = valid ? mm[k] : 0.0f;

            st[0][tid] = wg;
            st[1][tid] = wg * vr;
            st[2][tid] = wg * vr * vr;
            st[3][tid] = wg * vp;
            st[4][tid] = wg * vp * vp;
            st[5][tid] = wg * vzc[k];
            st[6][tid] = wg * vzc[k] * vzc[k];
            st[7][tid] = binf;
            __syncthreads();

            // ---- two 32-particle MFMA batches over this wave's 64 columns ----
            #pragma unroll
            for (int b = 0; b < 2; ++b) {
                const int c0 = (w << 6) + (b << 5) + (g << 3);  // 64w+32b+8g

                // B fragment: feats[k=8g+j][col] ; cols 7..15 are zero
                unsigned bu0 = 0, bu1 = 0, bu2 = 0, bu3 = 0;
                if (col < NFEAT) {
                    const float* rowp = &st[col][c0];
                    float4 lo = *(const float4*)rowp;
                    float4 hi = *(const float4*)(rowp + 4);
                    bu0 = pk2bf(lo.x, lo.y);
                    bu1 = pk2bf(lo.z, lo.w);
                    bu2 = pk2bf(hi.x, hi.y);
                    bu3 = pk2bf(hi.z, hi.w);
                }
                union { unsigned u[4]; short8 v; } B;
                B.u[0]=bu0; B.u[1]=bu1; B.u[2]=bu2; B.u[3]=bu3;

                // bins of this k-group (same 8 addrs for all 16 lanes: broadcast)
                const float* bp = &st[7][c0];
                float4 blo = *(const float4*)bp;
                float4 bhi = *(const float4*)(bp + 4);
                float bn[8] = {blo.x, blo.y, blo.z, blo.w,
                               bhi.x, bhi.y, bhi.z, bhi.w};

                // A fragment per bin-tile: onehot[row = col+16t][k=8g+j]
                #pragma unroll
                for (int t = 0; t < 4; ++t) {
                    float rT = (float)(col + 16*t);
                    union { unsigned u[4]; short8 v; } A;
                    #pragma unroll
                    for (int jp = 0; jp < 4; ++jp) {
                        unsigned lo = (bn[2*jp]   == rT) ? 0x00003F80u : 0u;
                        unsigned hi = (bn[2*jp+1] == rT) ? 0x3F800000u : 0u;
                        A.u[jp] = lo | hi;
                    }
                    acc[t] = __builtin_amdgcn_mfma_f32_16x16x32_bf16(
                                 A.v, B.v, acc[t], 0, 0, 0);
                }
            }
            __syncthreads();   // protect staging buffer before next k's writes
        }
    }

    // ---- write per-wave tiles to LDS (each mg[w] cell written exactly once) ----
    {
        const int g2 = lane >> 4;
        if (col < NFEAT) {
            #pragma unroll
            for (int t = 0; t < 4; ++t) {
                #pragma unroll
                for (int r = 0; r < 4; ++r) {
                    int bin = 16*t + 4*g2 + r;   // D: col=lane&15, row=(lane>>4)*4+r
                    if (bin < R_BINS)
                        mg[w][bin * NFEAT + col] = acc[t][r];
                }
            }
        }
    }
    __syncthreads();

    for (int i = tid; i < HSZ; i += blockDim.x) {
        float s = mg[0][i] + mg[1][i] + mg[2][i] + mg[3][i];
        atomicAdd(ghist + i, s);
    }

    // ---- exact scalar tail (n % 4 particles), handled once by block 0 ----
    if (blockIdx.x == 0 && tid < (n & 3)) {
        int p = (nquads << 2) + tid;
        float x = pos[3*p], y = pos[3*p + 1];
        float r = sqrtf(x*x + y*y);
        int bin = (int)floorf(r * 5.0f);
        if (bin >= 0 && bin < R_BINS && r > 0.0f) {
            float invr = 1.0f / r;
            float vxs = vel[3*p], vys = vel[3*p+1], vzs = vel[3*p+2];
            float vr = (x*vxs + y*vys) * invr;
            float vp = (y*vxs - x*vys) * invr;
            float wg = mass[p];
            float* bptr = ghist + bin * NFEAT;
            atomicAdd(bptr + 0, wg);
            atomicAdd(bptr + 1, wg * vr);
            atomicAdd(bptr + 2, wg * vr * vr);
            atomicAdd(bptr + 3, wg * vp);
            atomicAdd(bptr + 4, wg * vp * vp);
            atomicAdd(bptr + 5, wg * vzs);
            atomicAdd(bptr + 6, wg * vzs * vzs);
        }
    }
}

__global__ void disk_finalize_kernel(const float* __restrict__ gh,
                                     float* __restrict__ out)
{
    int b = threadIdx.x;
    if (b >= R_BINS) return;
    const float* s = gh + b * NFEAT;
    float inv  = 1.0f / s[0];
    float vr_m = s[1] * inv, vr2 = s[2] * inv;
    float vp_m = s[3] * inv, vp2 = s[4] * inv;
    float vz_m = s[5] * inv, vz2 = s[6] * inv;
    out[0 * R_BINS + b] = vp_m;
    out[1 * R_BINS + b] = sqrtf(vp2 - vp_m * vp_m);
    out[2 * R_BINS + b] = vr_m;
    out[3 * R_BINS + b] = sqrtf(vr2 - vr_m * vr_m);
    out[4 * R_BINS + b] = vz_m;
    out[5 * R_BINS + b] = sqrtf(vz2 - vz_m * vz_m);
}

extern "C" void kernel_launch(void* const* d_in, const int* in_sizes, int n_in,
                              void* d_out, int out_size, void* d_ws, size_t ws_size,
                              hipStream_t stream)
{
    const float* pos  = (const float*)d_in[0];
    const float* vel  = (const float*)d_in[1];
    const float* mass = (const float*)d_in[2];
    float* out   = (float*)d_out;
    float* ghist = (float*)d_ws;
    int n = in_sizes[2];   // masses: one per particle

    hipMemsetAsync(ghist, 0, HSZ * sizeof(float), stream);

    disk_hist_kernel<<<2048, 256, 0, stream>>>(pos, vel, mass, ghist, n);
    disk_finalize_kernel<<<1, 64, 0, stream>>>(ghist, out);
}